// Round 1
// baseline (595.516 us; speedup 1.0000x reference)
//
#include <hip/hip_runtime.h>
#include <math.h>

#define IMG 800.0f
#define SCORE_TH 0.25f
#define NMS_TH 0.5f
#define MAXDET 100
#define BBOX_CLIP 4.135166556742356f /* log(1000/16) */

constexpr int kB = 16;
constexpr int kN = 4000;
constexpr int kD = 1024;

// ---------------------------------------------------------------------------
// Kernel 1: fused head matmul (6 needed channels only) + softmax + box decode.
// One wave per row; per-lane weight slice held in registers (24 float4).
// ---------------------------------------------------------------------------
__global__ __launch_bounds__(256, 2) void head_kernel(
    const float* __restrict__ feats, const float* __restrict__ proposals,
    const float* __restrict__ Wc, const float* __restrict__ bc,
    const float* __restrict__ Wb, const float* __restrict__ bb,
    float* __restrict__ out, float* __restrict__ ws_scores,
    float* __restrict__ ws_boxes) {
  const int lane = threadIdx.x & 63;
  const int waveId = (blockIdx.x * blockDim.x + threadIdx.x) >> 6;
  const int nWaves = (gridDim.x * blockDim.x) >> 6;

  // Lane's d-slice: d = ch*256 + lane*4 + {0..3}, ch = 0..3. Preload weights.
  const float4* Wc4 = (const float4*)Wc;  // (2,1024) -> 2*256 float4
  const float4* Wb4 = (const float4*)Wb;  // (8,1024) -> 8*256 float4
  float4 w0[4], w1[4], w4[4], w5[4], w6[4], w7[4];
#pragma unroll
  for (int ch = 0; ch < 4; ++ch) {
    int idx = ch * 64 + lane;
    w0[ch] = Wc4[0 * 256 + idx];
    w1[ch] = Wc4[1 * 256 + idx];
    w4[ch] = Wb4[4 * 256 + idx];
    w5[ch] = Wb4[5 * 256 + idx];
    w6[ch] = Wb4[6 * 256 + idx];
    w7[ch] = Wb4[7 * 256 + idx];
  }
  const float bc0 = bc[0], bc1 = bc[1];
  const float bb4 = bb[4], bb5 = bb[5], bb6 = bb[6], bb7 = bb[7];

  const int R = kB * kN;
  for (int row = waveId; row < R; row += nWaves) {
    const float4* F = (const float4*)(feats + (size_t)row * kD);
    float a0 = 0.f, a1 = 0.f, a4 = 0.f, a5 = 0.f, a6 = 0.f, a7 = 0.f;
#pragma unroll
    for (int ch = 0; ch < 4; ++ch) {
      float4 f = F[ch * 64 + lane];
      a0 = fmaf(f.x, w0[ch].x, fmaf(f.y, w0[ch].y, fmaf(f.z, w0[ch].z, fmaf(f.w, w0[ch].w, a0))));
      a1 = fmaf(f.x, w1[ch].x, fmaf(f.y, w1[ch].y, fmaf(f.z, w1[ch].z, fmaf(f.w, w1[ch].w, a1))));
      a4 = fmaf(f.x, w4[ch].x, fmaf(f.y, w4[ch].y, fmaf(f.z, w4[ch].z, fmaf(f.w, w4[ch].w, a4))));
      a5 = fmaf(f.x, w5[ch].x, fmaf(f.y, w5[ch].y, fmaf(f.z, w5[ch].z, fmaf(f.w, w5[ch].w, a5))));
      a6 = fmaf(f.x, w6[ch].x, fmaf(f.y, w6[ch].y, fmaf(f.z, w6[ch].z, fmaf(f.w, w6[ch].w, a6))));
      a7 = fmaf(f.x, w7[ch].x, fmaf(f.y, w7[ch].y, fmaf(f.z, w7[ch].z, fmaf(f.w, w7[ch].w, a7))));
    }
#pragma unroll
    for (int off = 32; off; off >>= 1) {
      a0 += __shfl_xor(a0, off);
      a1 += __shfl_xor(a1, off);
      a4 += __shfl_xor(a4, off);
      a5 += __shfl_xor(a5, off);
      a6 += __shfl_xor(a6, off);
      a7 += __shfl_xor(a7, off);
    }
    if (lane == 0) {
      // softmax(2-class)[1] == sigmoid(l1-l0)
      float l0 = a0 + bc0, l1 = a1 + bc1;
      float score = 1.0f / (1.0f + __expf(l0 - l1));
      float sth = score > SCORE_TH ? score : 0.0f;

      float4 p = ((const float4*)proposals)[row];
      float w = p.z - p.x, h = p.w - p.y;
      float cx = p.x + 0.5f * w, cy = p.y + 0.5f * h;
      float dx = (a4 + bb4) * 0.1f;
      float dy = (a5 + bb5) * 0.1f;
      float dw = fminf((a6 + bb6) * 0.2f, BBOX_CLIP);
      float dh = fminf((a7 + bb7) * 0.2f, BBOX_CLIP);
      float pcx = fmaf(dx, w, cx), pcy = fmaf(dy, h, cy);
      float pw = __expf(dw) * w, ph = __expf(dh) * h;
      float x1 = fminf(fmaxf(pcx - 0.5f * pw, 0.f), IMG);
      float y1 = fminf(fmaxf(pcy - 0.5f * ph, 0.f), IMG);
      float x2 = fminf(fmaxf(pcx + 0.5f * pw, 0.f), IMG);
      float y2 = fminf(fmaxf(pcy + 0.5f * ph, 0.f), IMG);

      size_t ob = (size_t)row * 5;
      out[ob + 0] = x1;
      out[ob + 1] = y1;
      out[ob + 2] = x2;
      out[ob + 3] = y2;
      ws_scores[row] = sth;
      ((float4*)ws_boxes)[row] = make_float4(x1, y1, x2, y2);
    }
  }
}

// ---------------------------------------------------------------------------
// Kernel 2: greedy NMS, one block per batch image. 1024 threads, 4 rows each,
// boxes/scores/keep in registers. Exact reference semantics:
//  - argmax = first index of max (tie -> smallest n)
//  - keep[i] = (s[i] > 0)  (assignment, even when false)
//  - suppress iou > 0.5 over ALL boxes, plus explicit s[i] = 0
// ---------------------------------------------------------------------------
__global__ __launch_bounds__(1024) void nms_kernel(
    const float* __restrict__ ws_scores, const float* __restrict__ ws_boxes,
    float* __restrict__ out) {
  const int b = blockIdx.x;
  const int t = threadIdx.x;
  const float* sc = ws_scores + (size_t)b * kN;
  const float4* bx = (const float4*)ws_boxes + (size_t)b * kN;

  float s[4], orig[4], area[4];
  float4 box[4];
  bool keep[4];
#pragma unroll
  for (int k = 0; k < 4; ++k) {
    int n = k * 1024 + t;
    keep[k] = false;
    if (n < kN) {
      box[k] = bx[n];
      s[k] = sc[n];
      orig[k] = s[k];
      area[k] = fmaxf(box[k].z - box[k].x, 0.f) * fmaxf(box[k].w - box[k].y, 0.f);
    } else {
      box[k] = make_float4(0.f, 0.f, 0.f, 0.f);
      s[k] = -1e30f;  // never wins argmax (real scores >= 0)
      orig[k] = 0.f;
      area[k] = 0.f;
    }
  }

  __shared__ float wv[16];
  __shared__ int wi[16];
  __shared__ float s_bestv;
  __shared__ int s_besti;
  __shared__ float4 s_bbox;
  __shared__ float s_barea;

  for (int it = 0; it < MAXDET; ++it) {
    // local argmax over this thread's slots (ascending n, strict > keeps first)
    float bv = s[0];
    int bi = t;
#pragma unroll
    for (int k = 1; k < 4; ++k) {
      int n = k * 1024 + t;
      if (s[k] > bv) { bv = s[k]; bi = n; }
    }
    // wave argmax (tie -> smaller index)
#pragma unroll
    for (int off = 32; off; off >>= 1) {
      float ov = __shfl_xor(bv, off);
      int oi = __shfl_xor(bi, off);
      if (ov > bv || (ov == bv && oi < bi)) { bv = ov; bi = oi; }
    }
    if ((t & 63) == 0) { wv[t >> 6] = bv; wi[t >> 6] = bi; }
    __syncthreads();
    if (t < 16) {
      bv = wv[t];
      bi = wi[t];
#pragma unroll
      for (int off = 8; off; off >>= 1) {
        float ov = __shfl_xor(bv, off);
        int oi = __shfl_xor(bi, off);
        if (ov > bv || (ov == bv && oi < bi)) { bv = ov; bi = oi; }
      }
      if (t == 0) { s_bestv = bv; s_besti = bi; }
    }
    __syncthreads();
    const float mv = s_bestv;
    const int mi = s_besti;
    const bool valid = mv > 0.0f;
    const int ot = mi & 1023;
    const int ok = mi >> 10;
    if (t == ot) {
      keep[ok] = valid;  // assignment, matches keep.at[i].set(valid)
      s_bbox = box[ok];
      s_barea = area[ok];
      s[ok] = 0.0f;  // matches .at[i].set(0.0)
    }
    __syncthreads();
    const float4 bib = s_bbox;
    const float ba = s_barea;
#pragma unroll
    for (int k = 0; k < 4; ++k) {
      float ix1 = fmaxf(bib.x, box[k].x);
      float iy1 = fmaxf(bib.y, box[k].y);
      float ix2 = fminf(bib.z, box[k].z);
      float iy2 = fminf(bib.w, box[k].w);
      float inter = fmaxf(ix2 - ix1, 0.f) * fmaxf(iy2 - iy1, 0.f);
      float iou = inter / (ba + area[k] - inter + 1e-9f);
      if (iou > NMS_TH && s[k] > -1e29f) s[k] = 0.0f;  // keep sentinel intact
    }
  }

#pragma unroll
  for (int k = 0; k < 4; ++k) {
    int n = k * 1024 + t;
    if (n < kN) {
      out[((size_t)(b * kN + n)) * 5 + 4] = keep[k] ? orig[k] : 0.0f;
    }
  }
}

extern "C" void kernel_launch(void* const* d_in, const int* in_sizes, int n_in,
                              void* d_out, int out_size, void* d_ws,
                              size_t ws_size, hipStream_t stream) {
  const float* feats = (const float*)d_in[0];      // (16,4000,1024)
  const float* proposals = (const float*)d_in[1];  // (16,4000,4)
  const float* Wc = (const float*)d_in[2];         // (2,1024)
  const float* bc = (const float*)d_in[3];         // (2,)
  const float* Wb = (const float*)d_in[4];         // (8,1024)
  const float* bb = (const float*)d_in[5];         // (8,)
  float* out = (float*)d_out;                      // (16,4000,5)

  float* ws_scores = (float*)d_ws;               // 64000 floats
  float* ws_boxes = ws_scores + kB * kN;         // 64000*4 floats, 16B aligned

  head_kernel<<<512, 256, 0, stream>>>(feats, proposals, Wc, bc, Wb, bb, out,
                                       ws_scores, ws_boxes);
  nms_kernel<<<kB, 1024, 0, stream>>>(ws_scores, ws_boxes, out);
}

// Round 2
// 529.238 us; speedup vs baseline: 1.1252x; 1.1252x over previous
//
#include <hip/hip_runtime.h>
#include <math.h>

#define IMG 800.0f
#define SCORE_TH 0.25f
#define NMS_TH 0.5f
#define MAXDET 100
#define BBOX_CLIP 4.135166556742356f /* log(1000/16) */

constexpr int kB = 16;
constexpr int kN = 4000;
constexpr int kD = 1024;

// ---------------------------------------------------------------------------
// Kernel 1: fused head matmul (6 needed channels only) + softmax + box decode.
// One wave per row; per-lane weight slice held in registers (24 float4).
// ---------------------------------------------------------------------------
__global__ __launch_bounds__(256, 2) void head_kernel(
    const float* __restrict__ feats, const float* __restrict__ proposals,
    const float* __restrict__ Wc, const float* __restrict__ bc,
    const float* __restrict__ Wb, const float* __restrict__ bb,
    float* __restrict__ out, float* __restrict__ ws_scores,
    float* __restrict__ ws_boxes) {
  const int lane = threadIdx.x & 63;
  const int waveId = (blockIdx.x * blockDim.x + threadIdx.x) >> 6;
  const int nWaves = (gridDim.x * blockDim.x) >> 6;

  const float4* Wc4 = (const float4*)Wc;  // (2,1024) -> 2*256 float4
  const float4* Wb4 = (const float4*)Wb;  // (8,1024) -> 8*256 float4
  float4 w0[4], w1[4], w4[4], w5[4], w6[4], w7[4];
#pragma unroll
  for (int ch = 0; ch < 4; ++ch) {
    int idx = ch * 64 + lane;
    w0[ch] = Wc4[0 * 256 + idx];
    w1[ch] = Wc4[1 * 256 + idx];
    w4[ch] = Wb4[4 * 256 + idx];
    w5[ch] = Wb4[5 * 256 + idx];
    w6[ch] = Wb4[6 * 256 + idx];
    w7[ch] = Wb4[7 * 256 + idx];
  }
  const float bc0 = bc[0], bc1 = bc[1];
  const float bb4 = bb[4], bb5 = bb[5], bb6 = bb[6], bb7 = bb[7];

  const int R = kB * kN;
  for (int row = waveId; row < R; row += nWaves) {
    const float4* F = (const float4*)(feats + (size_t)row * kD);
    float a0 = 0.f, a1 = 0.f, a4 = 0.f, a5 = 0.f, a6 = 0.f, a7 = 0.f;
#pragma unroll
    for (int ch = 0; ch < 4; ++ch) {
      float4 f = F[ch * 64 + lane];
      a0 = fmaf(f.x, w0[ch].x, fmaf(f.y, w0[ch].y, fmaf(f.z, w0[ch].z, fmaf(f.w, w0[ch].w, a0))));
      a1 = fmaf(f.x, w1[ch].x, fmaf(f.y, w1[ch].y, fmaf(f.z, w1[ch].z, fmaf(f.w, w1[ch].w, a1))));
      a4 = fmaf(f.x, w4[ch].x, fmaf(f.y, w4[ch].y, fmaf(f.z, w4[ch].z, fmaf(f.w, w4[ch].w, a4))));
      a5 = fmaf(f.x, w5[ch].x, fmaf(f.y, w5[ch].y, fmaf(f.z, w5[ch].z, fmaf(f.w, w5[ch].w, a5))));
      a6 = fmaf(f.x, w6[ch].x, fmaf(f.y, w6[ch].y, fmaf(f.z, w6[ch].z, fmaf(f.w, w6[ch].w, a6))));
      a7 = fmaf(f.x, w7[ch].x, fmaf(f.y, w7[ch].y, fmaf(f.z, w7[ch].z, fmaf(f.w, w7[ch].w, a7))));
    }
#pragma unroll
    for (int off = 32; off; off >>= 1) {
      a0 += __shfl_xor(a0, off);
      a1 += __shfl_xor(a1, off);
      a4 += __shfl_xor(a4, off);
      a5 += __shfl_xor(a5, off);
      a6 += __shfl_xor(a6, off);
      a7 += __shfl_xor(a7, off);
    }
    if (lane == 0) {
      float l0 = a0 + bc0, l1 = a1 + bc1;
      float score = 1.0f / (1.0f + __expf(l0 - l1));
      float sth = score > SCORE_TH ? score : 0.0f;

      float4 p = ((const float4*)proposals)[row];
      float w = p.z - p.x, h = p.w - p.y;
      float cx = p.x + 0.5f * w, cy = p.y + 0.5f * h;
      float dx = (a4 + bb4) * 0.1f;
      float dy = (a5 + bb5) * 0.1f;
      float dw = fminf((a6 + bb6) * 0.2f, BBOX_CLIP);
      float dh = fminf((a7 + bb7) * 0.2f, BBOX_CLIP);
      float pcx = fmaf(dx, w, cx), pcy = fmaf(dy, h, cy);
      float pw = __expf(dw) * w, ph = __expf(dh) * h;
      float x1 = fminf(fmaxf(pcx - 0.5f * pw, 0.f), IMG);
      float y1 = fminf(fmaxf(pcy - 0.5f * ph, 0.f), IMG);
      float x2 = fminf(fmaxf(pcx + 0.5f * pw, 0.f), IMG);
      float y2 = fminf(fmaxf(pcy + 0.5f * ph, 0.f), IMG);

      size_t ob = (size_t)row * 5;
      out[ob + 0] = x1;
      out[ob + 1] = y1;
      out[ob + 2] = x2;
      out[ob + 3] = y2;
      ws_scores[row] = sth;
      ((float4*)ws_boxes)[row] = make_float4(x1, y1, x2, y2);
    }
  }
}

// ---------------------------------------------------------------------------
// Kernel 2: greedy NMS, one 256-thread block (4 waves) per batch image.
// 16 rows/thread in REGISTERS (row n = k*256 + t). Boxes mirrored in LDS so
// the winner box is a broadcast read. ONE barrier per iteration via
// double-buffered leader (val,idx) slots:
//   iter i: read buf[(i+1)&1] -> suppress -> argmax -> leaders write buf[i&1]
//           -> __syncthreads()
// Exact reference argmax semantics: max value, first (smallest) index.
// keep[i] = valid is an assignment (can clear), kept as a bitmask update.
// ---------------------------------------------------------------------------
__global__ __launch_bounds__(256) void nms_kernel(
    const float* __restrict__ ws_scores, const float* __restrict__ ws_boxes,
    float* __restrict__ out) {
  const int b = blockIdx.x;
  const int t = threadIdx.x;  // 0..255
  const int wave = t >> 6;
  const int lane = t & 63;

  __shared__ float4 Lbox[kN];     // 64000 B
  __shared__ float Lval[2][4];
  __shared__ int Lidx[2][4];

  const float* sc = ws_scores + (size_t)b * kN;
  const float4* bx = (const float4*)ws_boxes + (size_t)b * kN;

  float s[16], orig[16], area[16];
  float4 box[16];
  unsigned keep_mask = 0u;

#pragma unroll
  for (int k = 0; k < 16; ++k) {
    int n = k * 256 + t;
    if (n < kN) {
      box[k] = bx[n];
      s[k] = sc[n];
      orig[k] = s[k];
      area[k] = fmaxf(box[k].z - box[k].x, 0.f) * fmaxf(box[k].w - box[k].y, 0.f);
      Lbox[n] = box[k];
    } else {
      box[k] = make_float4(0.f, 0.f, 0.f, 0.f);  // inter==0 vs any real box
      s[k] = -1.0f;                              // never wins argmax
      orig[k] = 0.f;
      area[k] = 0.f;
    }
  }

  // Initial argmax (selection #1), leaders write parity-1 buffer.
  {
    float bv = s[0];
    int bi = t;
#pragma unroll
    for (int k = 1; k < 16; ++k)
      if (s[k] > bv) { bv = s[k]; bi = k * 256 + t; }
#pragma unroll
    for (int off = 32; off; off >>= 1) {
      float ov = __shfl_xor(bv, off);
      int oi = __shfl_xor(bi, off);
      if (ov > bv || (ov == bv && oi < bi)) { bv = ov; bi = oi; }
    }
    if (lane == 0) { Lval[1][wave] = bv; Lidx[1][wave] = bi; }
  }
  __syncthreads();

  for (int it = 0; it < MAXDET; ++it) {
    // Winner from previous reduction (all threads compute identically).
    const int pr = (it + 1) & 1;
    float wv = Lval[pr][0];
    int wi = Lidx[pr][0];
#pragma unroll
    for (int w = 1; w < 4; ++w) {
      float ov = Lval[pr][w];
      int oi = Lidx[pr][w];
      if (ov > wv || (ov == wv && oi < wi)) { wv = ov; wi = oi; }
    }
    const bool valid = wv > 0.0f;
    const float4 wb = Lbox[wi];  // broadcast, conflict-free
    const float wa =
        fmaxf(wb.z - wb.x, 0.f) * fmaxf(wb.w - wb.y, 0.f);
    const bool iOwn = (t == (wi & 255));
    const int oSlot = wi >> 8;

    // Fused: suppress + owner zero + keep assignment. Then local argmax.
    float bv;
    int bi;
#pragma unroll
    for (int k = 0; k < 16; ++k) {
      float ix = fminf(wb.z, box[k].z) - fmaxf(wb.x, box[k].x);
      float iy = fminf(wb.w, box[k].w) - fmaxf(wb.y, box[k].y);
      float inter = fmaxf(ix, 0.f) * fmaxf(iy, 0.f);
      float denom = wa + area[k] - inter + 1e-9f;
      bool sup = inter > 0.5f * denom;  // iou > NMS_TH
      bool sel = iOwn && (k == oSlot);
      if (sel) keep_mask = valid ? (keep_mask | (1u << k)) : (keep_mask & ~(1u << k));
      if (sup | sel) s[k] = 0.0f;  // sentinel rows: sup==sel==false always
      if (k == 0) {
        bv = s[0];
        bi = t;
      } else if (s[k] > bv) {
        bv = s[k];
        bi = k * 256 + t;
      }
    }
    // Wave argmax (max val, min idx on ties).
#pragma unroll
    for (int off = 32; off; off >>= 1) {
      float ov = __shfl_xor(bv, off);
      int oi = __shfl_xor(bi, off);
      if (ov > bv || (ov == bv && oi < bi)) { bv = ov; bi = oi; }
    }
    if (lane == 0) { Lval[it & 1][wave] = bv; Lidx[it & 1][wave] = bi; }
    __syncthreads();
  }

#pragma unroll
  for (int k = 0; k < 16; ++k) {
    int n = k * 256 + t;
    if (n < kN) {
      out[((size_t)(b * kN + n)) * 5 + 4] =
          (keep_mask >> k) & 1u ? orig[k] : 0.0f;
    }
  }
}

extern "C" void kernel_launch(void* const* d_in, const int* in_sizes, int n_in,
                              void* d_out, int out_size, void* d_ws,
                              size_t ws_size, hipStream_t stream) {
  const float* feats = (const float*)d_in[0];      // (16,4000,1024)
  const float* proposals = (const float*)d_in[1];  // (16,4000,4)
  const float* Wc = (const float*)d_in[2];         // (2,1024)
  const float* bc = (const float*)d_in[3];         // (2,)
  const float* Wb = (const float*)d_in[4];         // (8,1024)
  const float* bb = (const float*)d_in[5];         // (8,)
  float* out = (float*)d_out;                      // (16,4000,5)

  float* ws_scores = (float*)d_ws;        // 64000 floats
  float* ws_boxes = ws_scores + kB * kN;  // 64000*4 floats, 16B aligned

  head_kernel<<<512, 256, 0, stream>>>(feats, proposals, Wc, bc, Wb, bb, out,
                                       ws_scores, ws_boxes);
  nms_kernel<<<kB, 256, 0, stream>>>(ws_scores, ws_boxes, out);
}

// Round 3
// 526.142 us; speedup vs baseline: 1.1319x; 1.0059x over previous
//
#include <hip/hip_runtime.h>
#include <math.h>

#define IMG 800.0f
#define SCORE_TH 0.25f
#define NMS_TH 0.5f
#define MAXDET 100
#define BBOX_CLIP 4.135166556742356f /* log(1000/16) */

constexpr int kB = 16;
constexpr int kN = 4000;
constexpr int kD = 1024;

// ---------------------------------------------------------------------------
// Kernel 1: fused head matmul (6 needed channels only) + softmax + box decode.
// One wave per row; per-lane weight slice held in registers (24 float4).
// ---------------------------------------------------------------------------
__global__ __launch_bounds__(256, 2) void head_kernel(
    const float* __restrict__ feats, const float* __restrict__ proposals,
    const float* __restrict__ Wc, const float* __restrict__ bc,
    const float* __restrict__ Wb, const float* __restrict__ bb,
    float* __restrict__ out, float* __restrict__ ws_scores,
    float* __restrict__ ws_boxes) {
  const int lane = threadIdx.x & 63;
  const int waveId = (blockIdx.x * blockDim.x + threadIdx.x) >> 6;
  const int nWaves = (gridDim.x * blockDim.x) >> 6;

  const float4* Wc4 = (const float4*)Wc;  // (2,1024) -> 2*256 float4
  const float4* Wb4 = (const float4*)Wb;  // (8,1024) -> 8*256 float4
  float4 w0[4], w1[4], w4[4], w5[4], w6[4], w7[4];
#pragma unroll
  for (int ch = 0; ch < 4; ++ch) {
    int idx = ch * 64 + lane;
    w0[ch] = Wc4[0 * 256 + idx];
    w1[ch] = Wc4[1 * 256 + idx];
    w4[ch] = Wb4[4 * 256 + idx];
    w5[ch] = Wb4[5 * 256 + idx];
    w6[ch] = Wb4[6 * 256 + idx];
    w7[ch] = Wb4[7 * 256 + idx];
  }
  const float bc0 = bc[0], bc1 = bc[1];
  const float bb4 = bb[4], bb5 = bb[5], bb6 = bb[6], bb7 = bb[7];

  const int R = kB * kN;
  for (int row = waveId; row < R; row += nWaves) {
    const float4* F = (const float4*)(feats + (size_t)row * kD);
    float a0 = 0.f, a1 = 0.f, a4 = 0.f, a5 = 0.f, a6 = 0.f, a7 = 0.f;
#pragma unroll
    for (int ch = 0; ch < 4; ++ch) {
      float4 f = F[ch * 64 + lane];
      a0 = fmaf(f.x, w0[ch].x, fmaf(f.y, w0[ch].y, fmaf(f.z, w0[ch].z, fmaf(f.w, w0[ch].w, a0))));
      a1 = fmaf(f.x, w1[ch].x, fmaf(f.y, w1[ch].y, fmaf(f.z, w1[ch].z, fmaf(f.w, w1[ch].w, a1))));
      a4 = fmaf(f.x, w4[ch].x, fmaf(f.y, w4[ch].y, fmaf(f.z, w4[ch].z, fmaf(f.w, w4[ch].w, a4))));
      a5 = fmaf(f.x, w5[ch].x, fmaf(f.y, w5[ch].y, fmaf(f.z, w5[ch].z, fmaf(f.w, w5[ch].w, a5))));
      a6 = fmaf(f.x, w6[ch].x, fmaf(f.y, w6[ch].y, fmaf(f.z, w6[ch].z, fmaf(f.w, w6[ch].w, a6))));
      a7 = fmaf(f.x, w7[ch].x, fmaf(f.y, w7[ch].y, fmaf(f.z, w7[ch].z, fmaf(f.w, w7[ch].w, a7))));
    }
#pragma unroll
    for (int off = 32; off; off >>= 1) {
      a0 += __shfl_xor(a0, off);
      a1 += __shfl_xor(a1, off);
      a4 += __shfl_xor(a4, off);
      a5 += __shfl_xor(a5, off);
      a6 += __shfl_xor(a6, off);
      a7 += __shfl_xor(a7, off);
    }
    if (lane == 0) {
      float l0 = a0 + bc0, l1 = a1 + bc1;
      float score = 1.0f / (1.0f + __expf(l0 - l1));
      float sth = score > SCORE_TH ? score : 0.0f;

      float4 p = ((const float4*)proposals)[row];
      float w = p.z - p.x, h = p.w - p.y;
      float cx = p.x + 0.5f * w, cy = p.y + 0.5f * h;
      float dx = (a4 + bb4) * 0.1f;
      float dy = (a5 + bb5) * 0.1f;
      float dw = fminf((a6 + bb6) * 0.2f, BBOX_CLIP);
      float dh = fminf((a7 + bb7) * 0.2f, BBOX_CLIP);
      float pcx = fmaf(dx, w, cx), pcy = fmaf(dy, h, cy);
      float pw = __expf(dw) * w, ph = __expf(dh) * h;
      float x1 = fminf(fmaxf(pcx - 0.5f * pw, 0.f), IMG);
      float y1 = fminf(fmaxf(pcy - 0.5f * ph, 0.f), IMG);
      float x2 = fminf(fmaxf(pcx + 0.5f * pw, 0.f), IMG);
      float y2 = fminf(fmaxf(pcy + 0.5f * ph, 0.f), IMG);

      size_t ob = (size_t)row * 5;
      out[ob + 0] = x1;
      out[ob + 1] = y1;
      out[ob + 2] = x2;
      out[ob + 3] = y2;
      ws_scores[row] = sth;
      ((float4*)ws_boxes)[row] = make_float4(x1, y1, x2, y2);
    }
  }
}

// ---------------------------------------------------------------------------
// Kernel 2: greedy NMS, one 256-thread block (4 waves) per batch image.
// 16 rows/thread fully register-resident (row n = k*256 + t).
// __launch_bounds__(256,1): only 16 blocks exist chip-wide, occupancy is
// irrelevant — allow up to 512 VGPRs so box/s/area arrays never spill
// (round 2: VGPR_Count=88 < 112-reg live set -> scratch spills -> 4200 cy/it).
// One barrier per iteration via double-buffered leader slots.
// ---------------------------------------------------------------------------
__global__ __launch_bounds__(256, 1) void nms_kernel(
    const float* __restrict__ ws_scores, const float* __restrict__ ws_boxes,
    float* __restrict__ out) {
  const int b = blockIdx.x;
  const int t = threadIdx.x;  // 0..255
  const int wave = t >> 6;
  const int lane = t & 63;

  __shared__ float4 Lbox[kN];  // 64000 B
  __shared__ float Lval[2][4];
  __shared__ int Lidx[2][4];

  const float* sc = ws_scores + (size_t)b * kN;
  const float4* bx = (const float4*)ws_boxes + (size_t)b * kN;

  float s[16], areaE[16];  // areaE = area + 1e-9 (denominator bias folded in)
  float4 box[16];
  unsigned keep_mask = 0u;

#pragma unroll
  for (int k = 0; k < 16; ++k) {
    int n = k * 256 + t;
    if (n < kN) {
      box[k] = bx[n];
      s[k] = sc[n];
      areaE[k] = fmaxf(box[k].z - box[k].x, 0.f) *
                     fmaxf(box[k].w - box[k].y, 0.f) +
                 1e-9f;
      Lbox[n] = box[k];
    } else {
      box[k] = make_float4(0.f, 0.f, 0.f, 0.f);  // inter==0 vs any real box
      s[k] = -1.0f;                              // never wins argmax
      areaE[k] = 1e-9f;
    }
  }

  // Initial argmax (selection #1), leaders write parity-1 buffer.
  {
    float bv = s[0];
    int bi = t;
#pragma unroll
    for (int k = 1; k < 16; ++k)
      if (s[k] > bv) { bv = s[k]; bi = k * 256 + t; }
#pragma unroll
    for (int off = 32; off; off >>= 1) {
      float ov = __shfl_xor(bv, off);
      int oi = __shfl_xor(bi, off);
      if (ov > bv || (ov == bv && oi < bi)) { bv = ov; bi = oi; }
    }
    if (lane == 0) { Lval[1][wave] = bv; Lidx[1][wave] = bi; }
  }
  __syncthreads();

  for (int it = 0; it < MAXDET; ++it) {
    // Winner from previous reduction (all threads compute identically).
    const int pr = (it + 1) & 1;
    float wv = Lval[pr][0];
    int wi = Lidx[pr][0];
#pragma unroll
    for (int w = 1; w < 4; ++w) {
      float ov = Lval[pr][w];
      int oi = Lidx[pr][w];
      if (ov > wv || (ov == wv && oi < wi)) { wv = ov; wi = oi; }
    }
    const bool valid = wv > 0.0f;
    const float4 wb = Lbox[wi];  // broadcast, conflict-free
    const float wa = fmaxf(wb.z - wb.x, 0.f) * fmaxf(wb.w - wb.y, 0.f);
    const bool iOwn = (t == (wi & 255));
    const int oSlot = wi >> 8;
    const float2 wb_lo = make_float2(wb.x, wb.y);
    const float2 wb_hi = make_float2(wb.z, wb.w);

    // Fused: suppress + owner zero + keep assignment + local argmax.
    float bv;
    int bi;
#pragma unroll
    for (int k = 0; k < 16; ++k) {
      // float2 forms -> v_pk_max_f32 / v_pk_min_f32 / packed sub
      float2 lo, hi, d;
      lo.x = fmaxf(wb_lo.x, box[k].x);
      lo.y = fmaxf(wb_lo.y, box[k].y);
      hi.x = fminf(wb_hi.x, box[k].z);
      hi.y = fminf(wb_hi.y, box[k].w);
      d.x = hi.x - lo.x;
      d.y = hi.y - lo.y;
      float inter = fmaxf(d.x, 0.f) * fmaxf(d.y, 0.f);
      float denom = wa + areaE[k] - inter;
      bool sup = inter > 0.5f * denom;  // iou > NMS_TH
      bool sel = iOwn && (k == oSlot);
      if (sel)
        keep_mask = valid ? (keep_mask | (1u << k)) : (keep_mask & ~(1u << k));
      if (sup | sel) s[k] = 0.0f;  // sentinel rows: sup==sel==false always
      if (k == 0) {
        bv = s[0];
        bi = t;
      } else if (s[k] > bv) {
        bv = s[k];
        bi = k * 256 + t;
      }
    }
    // Wave argmax (max val, min idx on ties).
#pragma unroll
    for (int off = 32; off; off >>= 1) {
      float ov = __shfl_xor(bv, off);
      int oi = __shfl_xor(bi, off);
      if (ov > bv || (ov == bv && oi < bi)) { bv = ov; bi = oi; }
    }
    if (lane == 0) { Lval[it & 1][wave] = bv; Lidx[it & 1][wave] = bi; }
    __syncthreads();
  }

#pragma unroll
  for (int k = 0; k < 16; ++k) {
    int n = k * 256 + t;
    if (n < kN) {
      // ws_scores untouched by this kernel: re-read instead of keeping orig[]
      out[((size_t)(b * kN + n)) * 5 + 4] =
          (keep_mask >> k) & 1u ? sc[n] : 0.0f;
    }
  }
}

extern "C" void kernel_launch(void* const* d_in, const int* in_sizes, int n_in,
                              void* d_out, int out_size, void* d_ws,
                              size_t ws_size, hipStream_t stream) {
  const float* feats = (const float*)d_in[0];      // (16,4000,1024)
  const float* proposals = (const float*)d_in[1];  // (16,4000,4)
  const float* Wc = (const float*)d_in[2];         // (2,1024)
  const float* bc = (const float*)d_in[3];         // (2,)
  const float* Wb = (const float*)d_in[4];         // (8,1024)
  const float* bb = (const float*)d_in[5];         // (8,)
  float* out = (float*)d_out;                      // (16,4000,5)

  float* ws_scores = (float*)d_ws;        // 64000 floats
  float* ws_boxes = ws_scores + kB * kN;  // 64000*4 floats, 16B aligned

  head_kernel<<<512, 256, 0, stream>>>(feats, proposals, Wc, bc, Wb, bb, out,
                                       ws_scores, ws_boxes);
  nms_kernel<<<kB, 256, 0, stream>>>(ws_scores, ws_boxes, out);
}

// Round 4
// 444.567 us; speedup vs baseline: 1.3395x; 1.1835x over previous
//
#include <hip/hip_runtime.h>
#include <math.h>

#define IMG 800.0f
#define SCORE_TH 0.25f
#define NMS_TH 0.5f
#define MAXDET 100
#define BBOX_CLIP 4.135166556742356f /* log(1000/16) */

constexpr int kB = 16;
constexpr int kN = 4000;
constexpr int kD = 1024;

// ---------------------------------------------------------------------------
// Kernel 1: fused head matmul (6 needed channels only) + softmax + box decode.
// One wave per row; per-lane weight slice held in registers (24 float4).
// ---------------------------------------------------------------------------
__global__ __launch_bounds__(256, 2) void head_kernel(
    const float* __restrict__ feats, const float* __restrict__ proposals,
    const float* __restrict__ Wc, const float* __restrict__ bc,
    const float* __restrict__ Wb, const float* __restrict__ bb,
    float* __restrict__ out, float* __restrict__ ws_scores,
    float* __restrict__ ws_boxes) {
  const int lane = threadIdx.x & 63;
  const int waveId = (blockIdx.x * blockDim.x + threadIdx.x) >> 6;
  const int nWaves = (gridDim.x * blockDim.x) >> 6;

  const float4* Wc4 = (const float4*)Wc;  // (2,1024) -> 2*256 float4
  const float4* Wb4 = (const float4*)Wb;  // (8,1024) -> 8*256 float4
  float4 w0[4], w1[4], w4[4], w5[4], w6[4], w7[4];
#pragma unroll
  for (int ch = 0; ch < 4; ++ch) {
    int idx = ch * 64 + lane;
    w0[ch] = Wc4[0 * 256 + idx];
    w1[ch] = Wc4[1 * 256 + idx];
    w4[ch] = Wb4[4 * 256 + idx];
    w5[ch] = Wb4[5 * 256 + idx];
    w6[ch] = Wb4[6 * 256 + idx];
    w7[ch] = Wb4[7 * 256 + idx];
  }
  const float bc0 = bc[0], bc1 = bc[1];
  const float bb4 = bb[4], bb5 = bb[5], bb6 = bb[6], bb7 = bb[7];

  const int R = kB * kN;
  for (int row = waveId; row < R; row += nWaves) {
    const float4* F = (const float4*)(feats + (size_t)row * kD);
    float a0 = 0.f, a1 = 0.f, a4 = 0.f, a5 = 0.f, a6 = 0.f, a7 = 0.f;
#pragma unroll
    for (int ch = 0; ch < 4; ++ch) {
      float4 f = F[ch * 64 + lane];
      a0 = fmaf(f.x, w0[ch].x, fmaf(f.y, w0[ch].y, fmaf(f.z, w0[ch].z, fmaf(f.w, w0[ch].w, a0))));
      a1 = fmaf(f.x, w1[ch].x, fmaf(f.y, w1[ch].y, fmaf(f.z, w1[ch].z, fmaf(f.w, w1[ch].w, a1))));
      a4 = fmaf(f.x, w4[ch].x, fmaf(f.y, w4[ch].y, fmaf(f.z, w4[ch].z, fmaf(f.w, w4[ch].w, a4))));
      a5 = fmaf(f.x, w5[ch].x, fmaf(f.y, w5[ch].y, fmaf(f.z, w5[ch].z, fmaf(f.w, w5[ch].w, a5))));
      a6 = fmaf(f.x, w6[ch].x, fmaf(f.y, w6[ch].y, fmaf(f.z, w6[ch].z, fmaf(f.w, w6[ch].w, a6))));
      a7 = fmaf(f.x, w7[ch].x, fmaf(f.y, w7[ch].y, fmaf(f.z, w7[ch].z, fmaf(f.w, w7[ch].w, a7))));
    }
#pragma unroll
    for (int off = 32; off; off >>= 1) {
      a0 += __shfl_xor(a0, off);
      a1 += __shfl_xor(a1, off);
      a4 += __shfl_xor(a4, off);
      a5 += __shfl_xor(a5, off);
      a6 += __shfl_xor(a6, off);
      a7 += __shfl_xor(a7, off);
    }
    if (lane == 0) {
      float l0 = a0 + bc0, l1 = a1 + bc1;
      float score = 1.0f / (1.0f + __expf(l0 - l1));
      float sth = score > SCORE_TH ? score : 0.0f;

      float4 p = ((const float4*)proposals)[row];
      float w = p.z - p.x, h = p.w - p.y;
      float cx = p.x + 0.5f * w, cy = p.y + 0.5f * h;
      float dx = (a4 + bb4) * 0.1f;
      float dy = (a5 + bb5) * 0.1f;
      float dw = fminf((a6 + bb6) * 0.2f, BBOX_CLIP);
      float dh = fminf((a7 + bb7) * 0.2f, BBOX_CLIP);
      float pcx = fmaf(dx, w, cx), pcy = fmaf(dy, h, cy);
      float pw = __expf(dw) * w, ph = __expf(dh) * h;
      float x1 = fminf(fmaxf(pcx - 0.5f * pw, 0.f), IMG);
      float y1 = fminf(fmaxf(pcy - 0.5f * ph, 0.f), IMG);
      float x2 = fminf(fmaxf(pcx + 0.5f * pw, 0.f), IMG);
      float y2 = fminf(fmaxf(pcy + 0.5f * ph, 0.f), IMG);

      size_t ob = (size_t)row * 5;
      out[ob + 0] = x1;
      out[ob + 1] = y1;
      out[ob + 2] = x2;
      out[ob + 3] = y2;
      ws_scores[row] = sth;
      ((float4*)ws_boxes)[row] = make_float4(x1, y1, x2, y2);
    }
  }
}

// ---------------------------------------------------------------------------
// DPP-based wave argmax on packed u64 keys: VALU-latency cross-lane instead of
// ds_bpermute (~120 cy/stage). Zero-fill (bound_ctrl + old=0) is safe: all
// real keys are > 0, so a 0 candidate never wins.
// ---------------------------------------------------------------------------
template <int CTRL>
__device__ __forceinline__ unsigned long long dpp_max_u64(unsigned long long k) {
  int lo = __builtin_amdgcn_update_dpp(0, (int)(unsigned)k, CTRL, 0xF, 0xF, true);
  int hi =
      __builtin_amdgcn_update_dpp(0, (int)(unsigned)(k >> 32), CTRL, 0xF, 0xF, true);
  unsigned long long o = ((unsigned long long)(unsigned)hi << 32) | (unsigned)lo;
  return o > k ? o : k;
}

__device__ __forceinline__ unsigned long long wave_max_u64(unsigned long long k) {
  k = dpp_max_u64<0x121>(k);  // row_ror:1
  k = dpp_max_u64<0x122>(k);  // row_ror:2
  k = dpp_max_u64<0x124>(k);  // row_ror:4
  k = dpp_max_u64<0x128>(k);  // row_ror:8   (every lane: 16-lane row max)
  k = dpp_max_u64<0x142>(k);  // row_bcast15 (rows 1,3 pick up rows 0,2)
  k = dpp_max_u64<0x143>(k);  // row_bcast31 (lane 63: wave max)
  return k;
}

// ---------------------------------------------------------------------------
// Kernel 2: greedy NMS, one 256-thread block (4 waves) per batch image.
// State per thread (row n = k*256 + t): khi[16] = score bits (suppress -> 0),
// box[16], areaE[16]. Key = (khi << 32) | ~n: max-key == reference argmax with
// first-index tie-break; sentinels (khi=0, n>=4000) lose to all real rows;
// all-suppressed case picks row 0 with valid=false (keep-revocation exact).
// One barrier/iter, double-buffered 4-wave leader keys in LDS.
// ---------------------------------------------------------------------------
__global__ __launch_bounds__(256, 1) void nms_kernel(
    const float* __restrict__ ws_scores, const float* __restrict__ ws_boxes,
    float* __restrict__ out) {
  const int b = blockIdx.x;
  const int t = threadIdx.x;  // 0..255
  const int wave = t >> 6;
  const int lane = t & 63;

  __shared__ float4 Lbox[kN];              // 64000 B
  __shared__ unsigned long long Lkey[2][4];

  const float* sc = ws_scores + (size_t)b * kN;
  const float4* bx = (const float4*)ws_boxes + (size_t)b * kN;

  unsigned khi[16];
  float areaE[16];  // area + 1e-9
  float4 box[16];
  unsigned keep_mask = 0u;
  const unsigned nt = ~(unsigned)t;  // ~(0*256+t); slot k low word = nt - 256k

#pragma unroll
  for (int k = 0; k < 16; ++k) {
    int n = k * 256 + t;
    if (n < kN) {
      box[k] = bx[n];
      khi[k] = __float_as_uint(sc[n]);  // scores >= 0: bits monotone
      areaE[k] = fmaxf(box[k].z - box[k].x, 0.f) *
                     fmaxf(box[k].w - box[k].y, 0.f) +
                 1e-9f;
      Lbox[n] = box[k];
    } else {
      box[k] = make_float4(0.f, 0.f, 0.f, 0.f);  // inter==0 vs any real box
      khi[k] = 0u;
      areaE[k] = 1e-9f;
    }
  }

  auto reduce_publish = [&](int parity) {
    unsigned long long lk[16];
#pragma unroll
    for (int k = 0; k < 16; ++k)
      lk[k] = ((unsigned long long)khi[k] << 32) |
              (unsigned long long)(nt - (unsigned)(k * 256));
#pragma unroll
    for (int k = 0; k < 8; ++k) lk[k] = lk[k] > lk[k + 8] ? lk[k] : lk[k + 8];
#pragma unroll
    for (int k = 0; k < 4; ++k) lk[k] = lk[k] > lk[k + 4] ? lk[k] : lk[k + 4];
    lk[0] = lk[0] > lk[2] ? lk[0] : lk[2];
    lk[1] = lk[1] > lk[3] ? lk[1] : lk[3];
    lk[0] = lk[0] > lk[1] ? lk[0] : lk[1];
    unsigned long long wkey = wave_max_u64(lk[0]);
    if (lane == 63) Lkey[parity][wave] = wkey;
  };

  reduce_publish(1);  // loop it=0 reads parity (0+1)&1 = 1
  __syncthreads();

  for (int it = 0; it < MAXDET; ++it) {
    const int pr = (it + 1) & 1;
    unsigned long long wk = Lkey[pr][0];
    unsigned long long k1 = Lkey[pr][1];
    unsigned long long k2 = Lkey[pr][2];
    unsigned long long k3 = Lkey[pr][3];
    wk = wk > k1 ? wk : k1;
    k2 = k2 > k3 ? k2 : k3;
    wk = wk > k2 ? wk : k2;
    // Uniform across the block -> scalarize the decode.
    const unsigned whi = (unsigned)__builtin_amdgcn_readfirstlane((int)(wk >> 32));
    const unsigned wlo = (unsigned)__builtin_amdgcn_readfirstlane((int)(unsigned)wk);
    const unsigned wn = ~wlo;  // winner row, always < kN
    const bool valid = whi != 0u;
    const float4 wb = Lbox[wn];  // broadcast read
    const float wa = fmaxf(wb.z - wb.x, 0.f) * fmaxf(wb.w - wb.y, 0.f);
    const bool iOwn = ((unsigned)t == (wn & 255u));
    const int oSlot = (int)(wn >> 8);
    if (iOwn) {
      unsigned bit = 1u << oSlot;
      keep_mask = valid ? (keep_mask | bit) : (keep_mask & ~bit);
    }
#pragma unroll
    for (int k = 0; k < 16; ++k) {
      float dx = fminf(wb.z, box[k].z) - fmaxf(wb.x, box[k].x);
      float dy = fminf(wb.w, box[k].w) - fmaxf(wb.y, box[k].y);
      float inter3 = 3.0f * fmaxf(dx, 0.f) * fmaxf(dy, 0.f);
      // iou > 0.5  <=>  3*inter > wa + area + 1e-9
      bool sup = inter3 > wa + areaE[k];
      if (sup || (iOwn && k == oSlot)) khi[k] = 0u;
    }
    reduce_publish(it & 1);
    __syncthreads();
  }

#pragma unroll
  for (int k = 0; k < 16; ++k) {
    int n = k * 256 + t;
    if (n < kN) {
      // ws_scores untouched by this kernel: re-read instead of keeping orig[]
      out[((size_t)(b * kN + n)) * 5 + 4] =
          (keep_mask >> k) & 1u ? sc[n] : 0.0f;
    }
  }
}

extern "C" void kernel_launch(void* const* d_in, const int* in_sizes, int n_in,
                              void* d_out, int out_size, void* d_ws,
                              size_t ws_size, hipStream_t stream) {
  const float* feats = (const float*)d_in[0];      // (16,4000,1024)
  const float* proposals = (const float*)d_in[1];  // (16,4000,4)
  const float* Wc = (const float*)d_in[2];         // (2,1024)
  const float* bc = (const float*)d_in[3];         // (2,)
  const float* Wb = (const float*)d_in[4];         // (8,1024)
  const float* bb = (const float*)d_in[5];         // (8,)
  float* out = (float*)d_out;                      // (16,4000,5)

  float* ws_scores = (float*)d_ws;        // 64000 floats
  float* ws_boxes = ws_scores + kB * kN;  // 64000*4 floats, 16B aligned

  head_kernel<<<512, 256, 0, stream>>>(feats, proposals, Wc, bc, Wb, bb, out,
                                       ws_scores, ws_boxes);
  nms_kernel<<<kB, 256, 0, stream>>>(ws_scores, ws_boxes, out);
}